// Round 9
// baseline (113.740 us; speedup 1.0000x reference)
//
#include <hip/hip_runtime.h>
#include <hip/hip_bf16.h>

// GT2RBFnn: B=4096, N=8, M=16, ASN=101, P=3
// s = sum_n (x-mu)^2*k = sum_n x*(x*k + (-2 mu k)) + sum_n mu^2 k  (nested FMA)
// log2(e) folded into k so the hot loop uses exp2f (raw v_exp_f32).
// Table c4[(m*N+n)*ASN+a] = {kl, -2*mu*kl, ku, -2*mu*ku}   (206,848 B)
//       c3[m*ASN+a]       = {sum_n mu^2*kl, sum_n mu^2*ku} ( 12,928 B)
// KB=8 rows/block: table L2 traffic = 512 blocks * 207 KB = 106 MB (~3 us).
// Inner loop: coalesced float4 loads + 2 nested FMAs per (m,n,row), zero LDS.

constexpr int B = 4096, N = 8, M = 16, ASN = 101, P = 3;
constexpr int KB = 8;                 // batch rows per block (thread-level reuse)
constexpr int NBLK = B / KB;          // 512 blocks
constexpr float LOG2E = 1.4426950408889634f;

// ---------------- kernel 1: build constant tables ----------------
__global__ void build_ctab(const float* __restrict__ mu,
                           const float* __restrict__ sigma,
                           const float* __restrict__ delta_sig,
                           const float* __restrict__ alpha,
                           float4* __restrict__ c4,
                           float2* __restrict__ c3) {
    int idx = blockIdx.x * blockDim.x + threadIdx.x;
    constexpr int MNA = M * N * ASN;
    if (idx < MNA) {
        int a = idx % ASN;
        int mn = idx / ASN;
        int m = mn / N, n = mn % N;
        int nm = n * M + m;                    // input layout (n, m)
        float dl = delta_sig[nm] * 0.5f;       // delta
        float sg = sigma[nm] + dl;             // sig
        float oma = 1.0f - alpha[a];
        float dlo = sg + dl * oma;
        float dup = sg - dl * oma;
        float kl = (-0.5f * LOG2E) / (dlo * dlo);
        float ku = (-0.5f * LOG2E) / (dup * dup);
        float mv = mu[nm];
        c4[idx] = make_float4(kl, -2.0f * mv * kl, ku, -2.0f * mv * ku);
    } else if (idx < MNA + M * ASN) {
        int j = idx - MNA;
        int a = j % ASN, m = j / ASN;
        float oma = 1.0f - alpha[a];
        float sl = 0.f, su = 0.f;
        for (int n = 0; n < N; ++n) {
            int nm = n * M + m;
            float dl = delta_sig[nm] * 0.5f;
            float sg = sigma[nm] + dl;
            float dlo = sg + dl * oma;
            float dup = sg - dl * oma;
            float kl = (-0.5f * LOG2E) / (dlo * dlo);
            float ku = (-0.5f * LOG2E) / (dup * dup);
            float mv = mu[nm];
            sl = fmaf(mv * mv, kl, sl);
            su = fmaf(mv * mv, ku, su);
        }
        c3[m * ASN + a] = make_float2(sl, su);
    }
}

// ---------------- kernel 2: main ----------------
__global__ __launch_bounds__(128) void gt2rbf_main(
    const float*  __restrict__ X,
    const float*  __restrict__ weights,
    const float*  __restrict__ bias,
    const float*  __restrict__ alpha,
    const float4* __restrict__ c4,
    const float2* __restrict__ c3,
    float* __restrict__ out)
{
    __shared__ float wl[M * P];
    __shared__ float red[2][KB * P + 1];

    const int t = threadIdx.x;
    const int bg = blockIdx.x;

    if (t < M * P) wl[t] = weights[t];

    // stage x for the block's 8 rows (block-uniform addresses)
    float xv[KB][N];
    const float* Xb = X + bg * (KB * N);
    #pragma unroll
    for (int i = 0; i < KB; ++i)
        #pragma unroll
        for (int n = 0; n < N; ++n)
            xv[i][n] = Xb[i * N + n];
    __syncthreads();

    float vals[KB * P + 1];
    #pragma unroll
    for (int k = 0; k < KB * P + 1; ++k) vals[k] = 0.f;

    if (t < ASN) {
        float av = alpha[t];
        float num[KB][P], den[KB];
        #pragma unroll
        for (int i = 0; i < KB; ++i) {
            den[i] = 0.f;
            #pragma unroll
            for (int p = 0; p < P; ++p) num[i][p] = 0.f;
        }

        #pragma unroll 2
        for (int m = 0; m < M; ++m) {
            float2 C = c3[m * ASN + t];
            float slo[KB], sup[KB];
            #pragma unroll
            for (int i = 0; i < KB; ++i) { slo[i] = C.x; sup[i] = C.y; }

            #pragma unroll
            for (int n = 0; n < N; ++n) {
                float4 c = c4[(m * N + n) * ASN + t];   // 16B/lane, coalesced
                #pragma unroll
                for (int i = 0; i < KB; ++i) {
                    float x = xv[i][n];
                    // x^2*k + x*(-2 mu k)  ==  x*(x*k + (-2 mu k))
                    slo[i] = fmaf(x, fmaf(x, c.x, c.y), slo[i]);
                    sup[i] = fmaf(x, fmaf(x, c.z, c.w), sup[i]);
                }
            }

            float w0 = wl[m * P + 0], w1 = wl[m * P + 1], w2 = wl[m * P + 2];
            #pragma unroll
            for (int i = 0; i < KB; ++i) {
                float f = exp2f(slo[i]) + exp2f(sup[i]);
                num[i][0] = fmaf(f, w0, num[i][0]);
                num[i][1] = fmaf(f, w1, num[i][1]);
                num[i][2] = fmaf(f, w2, num[i][2]);
                den[i] += f;
            }
        }

        #pragma unroll
        for (int i = 0; i < KB; ++i) {
            float s = av / den[i];                // alpha[a] * num/den
            vals[i * P + 0] = num[i][0] * s;
            vals[i * P + 1] = num[i][1] * s;
            vals[i * P + 2] = num[i][2] * s;
        }
        vals[KB * P] = av;
    }

    // block reduction over alpha: wave64 shuffle, then combine 2 waves via LDS
    #pragma unroll
    for (int off = 32; off > 0; off >>= 1)
        #pragma unroll
        for (int k = 0; k < KB * P + 1; ++k)
            vals[k] += __shfl_down(vals[k], off);

    const int w = t >> 6;
    if ((t & 63) == 0) {
        #pragma unroll
        for (int k = 0; k < KB * P + 1; ++k) red[w][k] = vals[k];
    }
    __syncthreads();

    if (t == 0) {
        float asum = red[0][KB * P] + red[1][KB * P];
        float inv = 1.0f / asum;
        #pragma unroll
        for (int i = 0; i < KB; ++i) {
            #pragma unroll
            for (int p = 0; p < P; ++p) {
                out[(bg * KB + i) * P + p] =
                    (red[0][i * P + p] + red[1][i * P + p]) * inv + bias[p];
            }
        }
    }
}

extern "C" void kernel_launch(void* const* d_in, const int* in_sizes, int n_in,
                              void* d_out, int out_size, void* d_ws, size_t ws_size,
                              hipStream_t stream) {
    const float* X         = (const float*)d_in[0];   // (B, N)
    const float* mu        = (const float*)d_in[1];   // (1, N, M, 1)
    const float* sigma     = (const float*)d_in[2];   // (1, N, M, 1)
    const float* delta_sig = (const float*)d_in[3];   // (1, N, M, 1)
    const float* weights   = (const float*)d_in[4];   // (M, P)
    const float* bias      = (const float*)d_in[5];   // (1, P)
    const float* alpha     = (const float*)d_in[6];   // (ASN,)
    float* out = (float*)d_out;

    constexpr int MNA = M * N * ASN;                  // 12928
    float4* c4 = (float4*)d_ws;                       // 206,848 B
    float2* c3 = (float2*)((char*)d_ws + MNA * sizeof(float4));  // 12,928 B

    constexpr int total = MNA + M * ASN;              // 14544
    build_ctab<<<(total + 255) / 256, 256, 0, stream>>>(mu, sigma, delta_sig, alpha, c4, c3);
    gt2rbf_main<<<NBLK, 128, 0, stream>>>(X, weights, bias, alpha, c4, c3, out);
}

// Round 15
// 107.410 us; speedup vs baseline: 1.0589x; 1.0589x over previous
//
#include <hip/hip_runtime.h>
#include <hip/hip_bf16.h>

// GT2RBFnn: B=4096, N=8, M=16, ASN=101, P=3
// s = sum_n (x-mu)^2*k = sum_n x*(x*k + (-2 mu k)) + sum_n mu^2 k  (nested FMA)
// log2(e) folded into k so the hot loop uses exp2f (raw v_exp_f32).
// Table c4[(m*N+n)*ASN+a] = {kl, -2*mu*kl, ku, -2*mu*ku}   (206,848 B)
//       c3[m*ASN+a]       = {sum_n mu^2*kl, sum_n mu^2*ku} ( 12,928 B)
// KB=4 rows/block (KB=8 spilled: VGPR=36, main 50us — round 9 post-mortem).
// 1024 blocks x 2 waves = 8 waves/CU. Inner loop: coalesced float4 + 2 nested
// FMAs per (m,n,row), zero LDS reads.

constexpr int B = 4096, N = 8, M = 16, ASN = 101, P = 3;
constexpr int KB = 4;                 // batch rows per block
constexpr int NBLK = B / KB;          // 1024 blocks
constexpr float LOG2E = 1.4426950408889634f;

// ---------------- kernel 1: build constant tables ----------------
__global__ void build_ctab(const float* __restrict__ mu,
                           const float* __restrict__ sigma,
                           const float* __restrict__ delta_sig,
                           const float* __restrict__ alpha,
                           float4* __restrict__ c4,
                           float2* __restrict__ c3) {
    int idx = blockIdx.x * blockDim.x + threadIdx.x;
    constexpr int MNA = M * N * ASN;
    if (idx < MNA) {
        int a = idx % ASN;
        int mn = idx / ASN;
        int m = mn / N, n = mn % N;
        int nm = n * M + m;                    // input layout (n, m)
        float dl = delta_sig[nm] * 0.5f;       // delta
        float sg = sigma[nm] + dl;             // sig
        float oma = 1.0f - alpha[a];
        float dlo = sg + dl * oma;
        float dup = sg - dl * oma;
        float kl = (-0.5f * LOG2E) / (dlo * dlo);
        float ku = (-0.5f * LOG2E) / (dup * dup);
        float mv = mu[nm];
        c4[idx] = make_float4(kl, -2.0f * mv * kl, ku, -2.0f * mv * ku);
    } else if (idx < MNA + M * ASN) {
        int j = idx - MNA;
        int a = j % ASN, m = j / ASN;
        float oma = 1.0f - alpha[a];
        float sl = 0.f, su = 0.f;
        for (int n = 0; n < N; ++n) {
            int nm = n * M + m;
            float dl = delta_sig[nm] * 0.5f;
            float sg = sigma[nm] + dl;
            float dlo = sg + dl * oma;
            float dup = sg - dl * oma;
            float kl = (-0.5f * LOG2E) / (dlo * dlo);
            float ku = (-0.5f * LOG2E) / (dup * dup);
            float mv = mu[nm];
            sl = fmaf(mv * mv, kl, sl);
            su = fmaf(mv * mv, ku, su);
        }
        c3[m * ASN + a] = make_float2(sl, su);
    }
}

// ---------------- kernel 2: main ----------------
__global__ __launch_bounds__(128) void gt2rbf_main(
    const float*  __restrict__ X,
    const float*  __restrict__ weights,
    const float*  __restrict__ bias,
    const float*  __restrict__ alpha,
    const float4* __restrict__ c4,
    const float2* __restrict__ c3,
    float* __restrict__ out)
{
    __shared__ float wl[M * P];
    __shared__ float red[2][KB * P + 1];

    const int t = threadIdx.x;
    const int bg = blockIdx.x;

    if (t < M * P) wl[t] = weights[t];

    // stage x for the block's 4 rows (block-uniform addresses)
    float xv[KB][N];
    const float* Xb = X + bg * (KB * N);
    #pragma unroll
    for (int i = 0; i < KB; ++i)
        #pragma unroll
        for (int n = 0; n < N; ++n)
            xv[i][n] = Xb[i * N + n];
    __syncthreads();

    float vals[KB * P + 1];
    #pragma unroll
    for (int k = 0; k < KB * P + 1; ++k) vals[k] = 0.f;

    if (t < ASN) {
        float av = alpha[t];
        float num[KB][P], den[KB];
        #pragma unroll
        for (int i = 0; i < KB; ++i) {
            den[i] = 0.f;
            #pragma unroll
            for (int p = 0; p < P; ++p) num[i][p] = 0.f;
        }

        #pragma unroll 2
        for (int m = 0; m < M; ++m) {
            float2 C = c3[m * ASN + t];
            float slo[KB], sup[KB];
            #pragma unroll
            for (int i = 0; i < KB; ++i) { slo[i] = C.x; sup[i] = C.y; }

            #pragma unroll
            for (int n = 0; n < N; ++n) {
                float4 c = c4[(m * N + n) * ASN + t];   // 16B/lane, coalesced
                #pragma unroll
                for (int i = 0; i < KB; ++i) {
                    float x = xv[i][n];
                    // x^2*k + x*(-2 mu k)  ==  x*(x*k + (-2 mu k))
                    slo[i] = fmaf(x, fmaf(x, c.x, c.y), slo[i]);
                    sup[i] = fmaf(x, fmaf(x, c.z, c.w), sup[i]);
                }
            }

            float w0 = wl[m * P + 0], w1 = wl[m * P + 1], w2 = wl[m * P + 2];
            #pragma unroll
            for (int i = 0; i < KB; ++i) {
                float f = exp2f(slo[i]) + exp2f(sup[i]);
                num[i][0] = fmaf(f, w0, num[i][0]);
                num[i][1] = fmaf(f, w1, num[i][1]);
                num[i][2] = fmaf(f, w2, num[i][2]);
                den[i] += f;
            }
        }

        #pragma unroll
        for (int i = 0; i < KB; ++i) {
            float s = av / den[i];                // alpha[a] * num/den
            vals[i * P + 0] = num[i][0] * s;
            vals[i * P + 1] = num[i][1] * s;
            vals[i * P + 2] = num[i][2] * s;
        }
        vals[KB * P] = av;
    }

    // block reduction over alpha: wave64 shuffle, then combine 2 waves via LDS
    #pragma unroll
    for (int off = 32; off > 0; off >>= 1)
        #pragma unroll
        for (int k = 0; k < KB * P + 1; ++k)
            vals[k] += __shfl_down(vals[k], off);

    const int w = t >> 6;
    if ((t & 63) == 0) {
        #pragma unroll
        for (int k = 0; k < KB * P + 1; ++k) red[w][k] = vals[k];
    }
    __syncthreads();

    if (t == 0) {
        float asum = red[0][KB * P] + red[1][KB * P];
        float inv = 1.0f / asum;
        #pragma unroll
        for (int i = 0; i < KB; ++i) {
            #pragma unroll
            for (int p = 0; p < P; ++p) {
                out[(bg * KB + i) * P + p] =
                    (red[0][i * P + p] + red[1][i * P + p]) * inv + bias[p];
            }
        }
    }
}

extern "C" void kernel_launch(void* const* d_in, const int* in_sizes, int n_in,
                              void* d_out, int out_size, void* d_ws, size_t ws_size,
                              hipStream_t stream) {
    const float* X         = (const float*)d_in[0];   // (B, N)
    const float* mu        = (const float*)d_in[1];   // (1, N, M, 1)
    const float* sigma     = (const float*)d_in[2];   // (1, N, M, 1)
    const float* delta_sig = (const float*)d_in[3];   // (1, N, M, 1)
    const float* weights   = (const float*)d_in[4];   // (M, P)
    const float* bias      = (const float*)d_in[5];   // (1, P)
    const float* alpha     = (const float*)d_in[6];   // (ASN,)
    float* out = (float*)d_out;

    constexpr int MNA = M * N * ASN;                  // 12928
    float4* c4 = (float4*)d_ws;                       // 206,848 B
    float2* c3 = (float2*)((char*)d_ws + MNA * sizeof(float4));  // 12,928 B

    constexpr int total = MNA + M * ASN;              // 14544
    build_ctab<<<(total + 255) / 256, 256, 0, stream>>>(mu, sigma, delta_sig, alpha, c4, c3);
    gt2rbf_main<<<NBLK, 128, 0, stream>>>(X, weights, bias, alpha, c4, c3, out);
}

// Round 16
// 86.153 us; speedup vs baseline: 1.3202x; 1.2467x over previous
//
#include <hip/hip_runtime.h>
#include <hip/hip_bf16.h>

// GT2RBFnn: B=4096, N=8, M=16, ASN=101, P=3
// Algebraic expansion: (x-mu)^2 * k = x^2*k + x*(-2 mu k) + mu^2 k, with
// log2(e) folded into k so the hot loop uses exp2f (raw v_exp_f32).
// Table c4[(m*N+n)*ASN+a] = {kl, -2*mu*kl, ku, -2*mu*ku}   (206,848 B)
//       c3[m*ASN+a]       = {sum_n mu^2*kl, sum_n mu^2*ku} ( 12,928 B)
// MEASURED-GOOD FORM (round 8: 86.3 us total, main < 39 us): KB=4, explicit
// x2 array, two independent FMAs per side. DO NOT "simplify" to nested
// fmaf(x, fmaf(x,k1,k2), s): the allocator then clamps to 24 VGPR and spills
// (round 15: main 43.7 us). Same failure at KB=8 (round 9: VGPR=36, 50.5 us).

constexpr int B = 4096, N = 8, M = 16, ASN = 101, P = 3;
constexpr int KB = 4;                 // batch rows per block
constexpr int NBLK = B / KB;          // 1024 blocks
constexpr float LOG2E = 1.4426950408889634f;

// ---------------- kernel 1: build constant tables ----------------
__global__ void build_ctab(const float* __restrict__ mu,
                           const float* __restrict__ sigma,
                           const float* __restrict__ delta_sig,
                           const float* __restrict__ alpha,
                           float4* __restrict__ c4,
                           float2* __restrict__ c3) {
    int idx = blockIdx.x * blockDim.x + threadIdx.x;
    constexpr int MNA = M * N * ASN;
    if (idx < MNA) {
        int a = idx % ASN;
        int mn = idx / ASN;
        int m = mn / N, n = mn % N;
        int nm = n * M + m;                    // input layout (n, m)
        float dl = delta_sig[nm] * 0.5f;       // delta
        float sg = sigma[nm] + dl;             // sig
        float oma = 1.0f - alpha[a];
        float dlo = sg + dl * oma;
        float dup = sg - dl * oma;
        float kl = (-0.5f * LOG2E) / (dlo * dlo);
        float ku = (-0.5f * LOG2E) / (dup * dup);
        float mv = mu[nm];
        c4[idx] = make_float4(kl, -2.0f * mv * kl, ku, -2.0f * mv * ku);
    } else if (idx < MNA + M * ASN) {
        int j = idx - MNA;
        int a = j % ASN, m = j / ASN;
        float oma = 1.0f - alpha[a];
        float sl = 0.f, su = 0.f;
        for (int n = 0; n < N; ++n) {
            int nm = n * M + m;
            float dl = delta_sig[nm] * 0.5f;
            float sg = sigma[nm] + dl;
            float dlo = sg + dl * oma;
            float dup = sg - dl * oma;
            float kl = (-0.5f * LOG2E) / (dlo * dlo);
            float ku = (-0.5f * LOG2E) / (dup * dup);
            float mv = mu[nm];
            sl = fmaf(mv * mv, kl, sl);
            su = fmaf(mv * mv, ku, su);
        }
        c3[m * ASN + a] = make_float2(sl, su);
    }
}

// ---------------- kernel 2: main ----------------
__global__ __launch_bounds__(128) void gt2rbf_main(
    const float*  __restrict__ X,
    const float*  __restrict__ weights,
    const float*  __restrict__ bias,
    const float*  __restrict__ alpha,
    const float4* __restrict__ c4,
    const float2* __restrict__ c3,
    float* __restrict__ out)
{
    __shared__ float wl[M * P];
    __shared__ float red[2][KB * P + 1];

    const int t = threadIdx.x;
    const int bg = blockIdx.x;

    if (t < M * P) wl[t] = weights[t];

    // stage x, x^2 for the block's 4 rows (block-uniform -> scalar-friendly)
    float xv[KB][N], x2[KB][N];
    const float* Xb = X + bg * (KB * N);
    #pragma unroll
    for (int i = 0; i < KB; ++i)
        #pragma unroll
        for (int n = 0; n < N; ++n) {
            float v = Xb[i * N + n];
            xv[i][n] = v;
            x2[i][n] = v * v;
        }
    __syncthreads();

    float vals[KB * P + 1];
    #pragma unroll
    for (int k = 0; k < KB * P + 1; ++k) vals[k] = 0.f;

    if (t < ASN) {
        float av = alpha[t];
        float num[KB][P], den[KB];
        #pragma unroll
        for (int i = 0; i < KB; ++i) {
            den[i] = 0.f;
            #pragma unroll
            for (int p = 0; p < P; ++p) num[i][p] = 0.f;
        }

        #pragma unroll 2
        for (int m = 0; m < M; ++m) {
            float2 C = c3[m * ASN + t];
            float slo[KB], sup[KB];
            #pragma unroll
            for (int i = 0; i < KB; ++i) { slo[i] = C.x; sup[i] = C.y; }

            #pragma unroll
            for (int n = 0; n < N; ++n) {
                float4 c = c4[(m * N + n) * ASN + t];   // 16B/lane, coalesced
                #pragma unroll
                for (int i = 0; i < KB; ++i) {
                    slo[i] = fmaf(x2[i][n], c.x, fmaf(xv[i][n], c.y, slo[i]));
                    sup[i] = fmaf(x2[i][n], c.z, fmaf(xv[i][n], c.w, sup[i]));
                }
            }

            float w0 = wl[m * P + 0], w1 = wl[m * P + 1], w2 = wl[m * P + 2];
            #pragma unroll
            for (int i = 0; i < KB; ++i) {
                float f = exp2f(slo[i]) + exp2f(sup[i]);
                num[i][0] = fmaf(f, w0, num[i][0]);
                num[i][1] = fmaf(f, w1, num[i][1]);
                num[i][2] = fmaf(f, w2, num[i][2]);
                den[i] += f;
            }
        }

        #pragma unroll
        for (int i = 0; i < KB; ++i) {
            float s = av / den[i];                // alpha[a] * num/den
            vals[i * P + 0] = num[i][0] * s;
            vals[i * P + 1] = num[i][1] * s;
            vals[i * P + 2] = num[i][2] * s;
        }
        vals[KB * P] = av;
    }

    // block reduction over alpha: wave64 shuffle, then combine 2 waves via LDS
    #pragma unroll
    for (int off = 32; off > 0; off >>= 1)
        #pragma unroll
        for (int k = 0; k < KB * P + 1; ++k)
            vals[k] += __shfl_down(vals[k], off);

    const int w = t >> 6;
    if ((t & 63) == 0) {
        #pragma unroll
        for (int k = 0; k < KB * P + 1; ++k) red[w][k] = vals[k];
    }
    __syncthreads();

    if (t == 0) {
        float asum = red[0][KB * P] + red[1][KB * P];
        float inv = 1.0f / asum;
        #pragma unroll
        for (int i = 0; i < KB; ++i) {
            #pragma unroll
            for (int p = 0; p < P; ++p) {
                out[(bg * KB + i) * P + p] =
                    (red[0][i * P + p] + red[1][i * P + p]) * inv + bias[p];
            }
        }
    }
}

extern "C" void kernel_launch(void* const* d_in, const int* in_sizes, int n_in,
                              void* d_out, int out_size, void* d_ws, size_t ws_size,
                              hipStream_t stream) {
    const float* X         = (const float*)d_in[0];   // (B, N)
    const float* mu        = (const float*)d_in[1];   // (1, N, M, 1)
    const float* sigma     = (const float*)d_in[2];   // (1, N, M, 1)
    const float* delta_sig = (const float*)d_in[3];   // (1, N, M, 1)
    const float* weights   = (const float*)d_in[4];   // (M, P)
    const float* bias      = (const float*)d_in[5];   // (1, P)
    const float* alpha     = (const float*)d_in[6];   // (ASN,)
    float* out = (float*)d_out;

    constexpr int MNA = M * N * ASN;                  // 12928
    float4* c4 = (float4*)d_ws;                       // 206,848 B
    float2* c3 = (float2*)((char*)d_ws + MNA * sizeof(float4));  // 12,928 B

    constexpr int total = MNA + M * ASN;              // 14544
    build_ctab<<<(total + 255) / 256, 256, 0, stream>>>(mu, sigma, delta_sig, alpha, c4, c3);
    gt2rbf_main<<<NBLK, 128, 0, stream>>>(X, weights, bias, alpha, c4, c3, out);
}